// Round 1
// baseline (646.548 us; speedup 1.0000x reference)
//
#include <hip/hip_runtime.h>
#include <math.h>

#define NBP   10000   // points per cloud
#define NBATCH 2
#define KNN   16
#define QT    32      // queries per block
#define PH    8       // candidate phases (threads per query)
#define TILE  2500    // candidates staged per LDS tile
#define NTHREADS 256

__global__ __launch_bounds__(NTHREADS)
void pfas_kernel(const float* __restrict__ feat,
                 const float* __restrict__ coord,
                 const float* __restrict__ W1,
                 const float* __restrict__ b1,
                 const float* __restrict__ gmm,
                 const float* __restrict__ bta,
                 const float* __restrict__ rmean,
                 const float* __restrict__ rvar,
                 const float* __restrict__ W2,
                 const float* __restrict__ b2,
                 float* __restrict__ out)
{
    __shared__ float4 s_cand[TILE];   // 40000 B; later aliased for the merge lists

    const int tid = threadIdx.x;
    const int ql  = tid >> 3;         // query slot within block: 0..31
    const int ph  = tid & 7;          // phase: candidate stripe mod 8
    const int b   = blockIdx.y;       // batch
    const int qi  = blockIdx.x * QT + ql;   // query index within batch
    const bool qv = (qi < NBP);
    const int g   = b * NBP + qi;     // global point index

    float qx = 0.f, qy = 0.f, qz = 0.f, qsq = 0.f;
    if (qv) {
        qx = coord[g*3+0]; qy = coord[g*3+1]; qz = coord[g*3+2];
        // match numpy: (x*x + y*y) + z*z, no fma contraction
        qsq = __fadd_rn(__fadd_rn(__fmul_rn(qx,qx), __fmul_rn(qy,qy)), __fmul_rn(qz,qz));
    }

    // per-lane top-16 (ascending by d2), register-resident, static indexing only
    float td[KNN]; int ti[KNN];
    #pragma unroll
    for (int s = 0; s < KNN; ++s) { td[s] = INFINITY; ti[s] = 0x7fffffff; }

    for (int t0 = 0; t0 < NBP; t0 += TILE) {
        const int tn = min(TILE, NBP - t0);
        __syncthreads();
        for (int c = tid; c < tn; c += NTHREADS) {
            const float* cp = coord + (size_t)(b*NBP + t0 + c) * 3;
            float x = cp[0], y = cp[1], z = cp[2];
            float sq = __fadd_rn(__fadd_rn(__fmul_rn(x,x), __fmul_rn(y,y)), __fmul_rn(z,z));
            s_cand[c] = make_float4(x, y, z, sq);
        }
        __syncthreads();
        if (qv) {
            for (int k = ph; k < tn; k += PH) {
                const float4 c = s_cand[k];
                // d2 = (sq_i + sq_j) - 2*dot, dot = (x*x' + y*y') + z*z'  (numpy order, no fma)
                float dot = __fadd_rn(__fadd_rn(__fmul_rn(qx,c.x), __fmul_rn(qy,c.y)), __fmul_rn(qz,c.z));
                float d2  = __fsub_rn(__fadd_rn(qsq, c.w), __fmul_rn(2.0f, dot));
                int j = t0 + k;
                if (d2 < td[KNN-1] && j != qi) {
                    // predicated sorted insert (strict < keeps earlier==lower index first)
                    float v = d2; int vi = j;
                    #pragma unroll
                    for (int s = 0; s < KNN; ++s) {
                        bool less = (v < td[s]);
                        float od = td[s]; int oi = ti[s];
                        td[s] = less ? v  : od;  ti[s] = less ? vi : oi;
                        v     = less ? od : v;   vi    = less ? oi : vi;
                    }
                }
            }
        }
    }

    __syncthreads();
    // dump per-lane sorted lists to LDS (alias the candidate tile)
    float2* lists = reinterpret_cast<float2*>(s_cand);   // 256*16*8 = 32768 B <= 40000 B
    #pragma unroll
    for (int s = 0; s < KNN; ++s)
        lists[tid*KNN + s] = make_float2(td[s], __int_as_float(ti[s]));
    __syncthreads();

    // one lane per query: 8-way merge of sorted lists -> final top-16, then PCA/MLP/blend
    if (tid < QT) {
        const int q  = tid;
        const int qq = blockIdx.x * QT + q;
        if (qq < NBP) {
            const int gq   = b * NBP + qq;
            const int base = (q * PH) * KNN;
            int h0=0,h1=0,h2=0,h3=0,h4=0,h5=0,h6=0,h7=0;
            int bi[KNN];
            float sumd = 0.f;
            #pragma unroll
            for (int o = 0; o < KNN; ++o) {
                float best = INFINITY; int besti = 0x7fffffff; int sel = -1;
                #define CHK(P, H) { float2 e = lists[base + (P)*KNN + (H)]; \
                    int ix = __float_as_int(e.y); \
                    if (e.x < best || (e.x == best && ix < besti)) { best = e.x; besti = ix; sel = (P); } }
                CHK(0,h0) CHK(1,h1) CHK(2,h2) CHK(3,h3)
                CHK(4,h4) CHK(5,h5) CHK(6,h6) CHK(7,h7)
                #undef CHK
                bi[o] = besti;
                sumd = __fadd_rn(sumd, sqrtf(fmaxf(best, 0.f)));
                h0 += (sel==0); h1 += (sel==1); h2 += (sel==2); h3 += (sel==3);
                h4 += (sel==4); h5 += (sel==5); h6 += (sel==6); h7 += (sel==7);
            }
            const float mean_dist = sumd * (1.0f / KNN);
            const float density   = 1.0f / (mean_dist + 1e-6f);

            // PCA over the 16 neighbors: two-pass (mean, then covariance), L1-hot gathers
            float mx = 0.f, my = 0.f, mz = 0.f;
            #pragma unroll
            for (int o = 0; o < KNN; ++o) {
                const float* cp = coord + (size_t)(b*NBP + bi[o]) * 3;
                mx += cp[0]; my += cp[1]; mz += cp[2];
            }
            mx *= (1.0f/KNN); my *= (1.0f/KNN); mz *= (1.0f/KNN);
            double cxx=0, cxy=0, cxz=0, cyy=0, cyz=0, czz=0;
            #pragma unroll
            for (int o = 0; o < KNN; ++o) {
                const float* cp = coord + (size_t)(b*NBP + bi[o]) * 3;
                double dx = (double)cp[0] - (double)mx;
                double dy = (double)cp[1] - (double)my;
                double dz = (double)cp[2] - (double)mz;
                cxx += dx*dx; cxy += dx*dy; cxz += dx*dz;
                cyy += dy*dy; cyz += dy*dz; czz += dz*dz;
            }
            const double inv = 1.0 / (KNN - 1);
            cxx *= inv; cxy *= inv; cxz *= inv; cyy *= inv; cyz *= inv; czz *= inv;

            // analytic eigenvalues of symmetric 3x3 (descending e0 >= e1 >= e2)
            double qm = (cxx + cyy + czz) / 3.0;
            double p1 = cxy*cxy + cxz*cxz + cyz*cyz;
            double b00 = cxx - qm, b11 = cyy - qm, b22 = czz - qm;
            double p2 = b00*b00 + b11*b11 + b22*b22 + 2.0*p1;
            double pp = sqrt(p2 / 6.0);
            double e0, e1, e2;
            if (pp < 1e-30) { e0 = e1 = e2 = qm; }
            else {
                double ip = 1.0 / pp;
                double c00 = b00*ip, c11 = b11*ip, c22 = b22*ip;
                double c01 = cxy*ip, c02 = cxz*ip, c12 = cyz*ip;
                double detB = c00*(c11*c22 - c12*c12)
                            - c01*(c01*c22 - c12*c02)
                            + c02*(c01*c12 - c11*c02);
                double r = detB * 0.5;
                r = fmin(1.0, fmax(-1.0, r));
                double phi = acos(r) / 3.0;
                e0 = qm + 2.0*pp*cos(phi);
                e2 = qm + 2.0*pp*cos(phi + 2.0943951023931953);  // +2pi/3
                e1 = 3.0*qm - e0 - e2;
            }
            const float lin = (float)((e0 - e1 - e2) / (e0 + e1 + e2 + 1e-6));

            // MLP: 64 -> 32 (BN inference + ReLU) -> 3 -> softmax
            const float* fr = feat + (size_t)gq * 64;
            float h[32];
            #pragma unroll
            for (int j = 0; j < 32; ++j) h[j] = b1[j];
            for (int i = 0; i < 64; ++i) {
                float fi = fr[i];
                #pragma unroll
                for (int j = 0; j < 32; ++j) h[j] = fmaf(fi, W1[i*32 + j], h[j]);
            }
            float l0 = b2[0], l1 = b2[1], l2 = b2[2];
            #pragma unroll
            for (int j = 0; j < 32; ++j) {
                float invstd = 1.0f / sqrtf(rvar[j] + 1e-5f);
                float hb = (h[j] - rmean[j]) * invstd * gmm[j] + bta[j];
                hb = fmaxf(hb, 0.f);
                l0 = fmaf(hb, W2[j*3+0], l0);
                l1 = fmaf(hb, W2[j*3+1], l1);
                l2 = fmaf(hb, W2[j*3+2], l2);
            }
            float m  = fmaxf(l0, fmaxf(l1, l2));
            float x0 = expf(l0 - m), x1 = expf(l1 - m), x2 = expf(l2 - m);
            float es = x0 + x1 + x2;
            float p0 = x0/es, pb = x1/es, pl = x2/es;

            float tower = (density*2.0f + p0) / 3.0f;
            float back  = (fmaxf(1.0f - lin, 1.0f - density) + pb) / 3.0f;
            float line  = (lin*2.0f + pl) / 3.0f;
            // GRID_T=(.1,.1,.1)  GRID_B=(1,1,1)  GRID_L=(.3,.3,1.5)
            float g01 = tower*0.1f + back*1.0f + line*0.3f + 1e-6f;
            float g2  = tower*0.1f + back*1.0f + line*1.5f + 1e-6f;
            out[(size_t)gq*3 + 0] = g01;
            out[(size_t)gq*3 + 1] = g01;
            out[(size_t)gq*3 + 2] = g2;
        }
    }
}

extern "C" void kernel_launch(void* const* d_in, const int* in_sizes, int n_in,
                              void* d_out, int out_size, void* d_ws, size_t ws_size,
                              hipStream_t stream) {
    const float* feat  = (const float*)d_in[0];
    const float* coord = (const float*)d_in[1];
    // d_in[2] = batch indices (layout is fixed: B=2 consecutive blocks of 10000) — unused
    const float* W1    = (const float*)d_in[3];
    const float* b1    = (const float*)d_in[4];
    const float* gmm   = (const float*)d_in[5];
    const float* bta   = (const float*)d_in[6];
    const float* rmean = (const float*)d_in[7];
    const float* rvar  = (const float*)d_in[8];
    const float* W2    = (const float*)d_in[9];
    const float* b2    = (const float*)d_in[10];
    float* out = (float*)d_out;

    dim3 grid((NBP + QT - 1) / QT, NBATCH);   // 313 x 2
    pfas_kernel<<<grid, NTHREADS, 0, stream>>>(feat, coord, W1, b1, gmm, bta,
                                               rmean, rvar, W2, b2, out);
}

// Round 2
// 489.927 us; speedup vs baseline: 1.3197x; 1.3197x over previous
//
#include <hip/hip_runtime.h>
#include <math.h>

#define NBP   10000   // points per cloud
#define NBATCH 2
#define KNN   16
#define QT    16      // queries per block
#define PH    16      // candidate phases (threads per query)
#define TILE  2000    // candidates staged per LDS tile (5 tiles; 125 cands/lane/tile exact)
#define NTHREADS 256
#define COLL  32      // collect slots per query in pass 2

__global__ __launch_bounds__(NTHREADS)
void pfas_kernel(const float* __restrict__ feat,
                 const float* __restrict__ coord,
                 const float* __restrict__ W1,
                 const float* __restrict__ b1,
                 const float* __restrict__ gmm,
                 const float* __restrict__ bta,
                 const float* __restrict__ rmean,
                 const float* __restrict__ rvar,
                 const float* __restrict__ W2,
                 const float* __restrict__ b2,
                 float* __restrict__ out)
{
    __shared__ float4 s_cand[TILE];          // 32000 B; aliased for pass-1 value lists
    __shared__ float  s_tau[QT];
    __shared__ float2 s_coll[QT][COLL];      // 4096 B
    __shared__ int    s_cnt[QT];

    const int tid = threadIdx.x;
    const int ql  = tid >> 4;                // query slot 0..15
    const int ph  = tid & 15;                // phase 0..15
    const int b   = blockIdx.y;
    const int qi  = blockIdx.x * QT + ql;    // 625*16 == 10000: always valid
    const int g   = b * NBP + qi;

    const float qx = coord[g*3+0], qy = coord[g*3+1], qz = coord[g*3+2];
    const float qsq = __fadd_rn(__fadd_rn(__fmul_rn(qx,qx), __fmul_rn(qy,qy)), __fmul_rn(qz,qz));

    if (tid < QT) s_cnt[tid] = 0;

    // ---------------- pass 1: branchless value-only top-16 ----------------
    float td[KNN];
    #pragma unroll
    for (int s = 0; s < KNN; ++s) td[s] = INFINITY;

    for (int t0 = 0; t0 < NBP; t0 += TILE) {
        __syncthreads();
        for (int c = tid; c < TILE; c += NTHREADS) {
            const float* cp = coord + (size_t)(b*NBP + t0 + c) * 3;
            float x = cp[0], y = cp[1], z = cp[2];
            float sq = __fadd_rn(__fadd_rn(__fmul_rn(x,x), __fmul_rn(y,y)), __fmul_rn(z,z));
            s_cand[c] = make_float4(x, y, z, sq);
        }
        __syncthreads();
        for (int k = ph; k < TILE; k += PH) {
            const float4 c = s_cand[k];
            float dot = __fadd_rn(__fadd_rn(__fmul_rn(qx,c.x), __fmul_rn(qy,c.y)), __fmul_rn(qz,c.z));
            float d2  = __fsub_rn(__fadd_rn(qsq, c.w), __fmul_rn(2.0f, dot));
            float v = (t0 + k == qi) ? INFINITY : d2;   // exclude self
            #pragma unroll
            for (int s = 0; s < KNN; ++s) {             // min/max bubble: 2 VALU/stage
                float t = td[s];
                td[s] = fminf(t, v);
                v     = fmaxf(t, v);
            }
        }
    }

    __syncthreads();
    // dump sorted value lists, interleaved layout (bank-conflict-free writes)
    float* lists = reinterpret_cast<float*>(s_cand);    // 16*256*4 = 16384 B <= 32000 B
    #pragma unroll
    for (int s = 0; s < KNN; ++s) lists[s*NTHREADS + tid] = td[s];
    __syncthreads();

    // one lane per query: 16-way merge of 16 sorted lists -> tau = 16th smallest value
    if (tid < QT) {
        const int lane0 = tid * PH;     // lists of query `tid` live at lanes lane0..lane0+15
        int h0=0,h1=0,h2=0,h3=0,h4=0,h5=0,h6=0,h7=0,h8=0,h9=0,h10=0,h11=0,h12=0,h13=0,h14=0,h15=0;
        float tau = INFINITY;
        #pragma unroll
        for (int o = 0; o < KNN; ++o) {
            float best = INFINITY; int sel = 0;
            #define CHK(P, H) { float e = ((H) < KNN) ? lists[(H)*NTHREADS + lane0 + (P)] : INFINITY; \
                                if (e < best) { best = e; sel = (P); } }
            CHK(0,h0)  CHK(1,h1)  CHK(2,h2)  CHK(3,h3)
            CHK(4,h4)  CHK(5,h5)  CHK(6,h6)  CHK(7,h7)
            CHK(8,h8)  CHK(9,h9)  CHK(10,h10) CHK(11,h11)
            CHK(12,h12) CHK(13,h13) CHK(14,h14) CHK(15,h15)
            #undef CHK
            tau = best;
            h0 += (sel==0);  h1 += (sel==1);  h2 += (sel==2);  h3 += (sel==3);
            h4 += (sel==4);  h5 += (sel==5);  h6 += (sel==6);  h7 += (sel==7);
            h8 += (sel==8);  h9 += (sel==9);  h10+= (sel==10); h11+= (sel==11);
            h12+= (sel==12); h13+= (sel==13); h14+= (sel==14); h15+= (sel==15);
        }
        s_tau[tid] = tau;
    }
    __syncthreads();

    // ---------------- pass 2: sparse collect of (d2, idx) with d2 <= tau ----------------
    const float tau = s_tau[ql];
    for (int t0 = 0; t0 < NBP; t0 += TILE) {
        __syncthreads();
        for (int c = tid; c < TILE; c += NTHREADS) {
            const float* cp = coord + (size_t)(b*NBP + t0 + c) * 3;
            float x = cp[0], y = cp[1], z = cp[2];
            float sq = __fadd_rn(__fadd_rn(__fmul_rn(x,x), __fmul_rn(y,y)), __fmul_rn(z,z));
            s_cand[c] = make_float4(x, y, z, sq);
        }
        __syncthreads();
        for (int k = ph; k < TILE; k += PH) {
            const float4 c = s_cand[k];
            float dot = __fadd_rn(__fadd_rn(__fmul_rn(qx,c.x), __fmul_rn(qy,c.y)), __fmul_rn(qz,c.z));
            float d2  = __fsub_rn(__fadd_rn(qsq, c.w), __fmul_rn(2.0f, dot));
            int j = t0 + k;
            if (d2 <= tau && j != qi) {
                int slot = atomicAdd(&s_cnt[ql], 1);
                if (slot < COLL) s_coll[ql][slot] = make_float2(d2, __int_as_float(j));
            }
        }
    }
    __syncthreads();

    // ---------------- tail: per-query select-16, PCA, MLP, blend ----------------
    if (tid < QT) {
        const int q  = tid;
        const int qq = blockIdx.x * QT + q;
        const int gq = b * NBP + qq;
        const int n  = min(s_cnt[q], COLL);

        int bi[KNN];
        float sumd = 0.f;
        #pragma unroll
        for (int o = 0; o < KNN; ++o) {
            float best = INFINITY; int besti = qq; int sl = -1;
            for (int e = 0; e < n; ++e) {
                float2 en = s_coll[q][e];
                int ix = __float_as_int(en.y);
                if (en.x < best || (en.x == best && ix < besti)) { best = en.x; besti = ix; sl = e; }
            }
            if (sl >= 0) s_coll[q][sl].x = INFINITY;   // pop
            bi[o] = besti;
            sumd = __fadd_rn(sumd, sqrtf(fmaxf(best, 0.f)));
        }
        const float mean_dist = sumd * (1.0f / KNN);
        const float density   = 1.0f / (mean_dist + 1e-6f);

        // PCA over the 16 neighbors: two-pass (mean, then covariance)
        float mx = 0.f, my = 0.f, mz = 0.f;
        #pragma unroll
        for (int o = 0; o < KNN; ++o) {
            const float* cp = coord + (size_t)(b*NBP + bi[o]) * 3;
            mx += cp[0]; my += cp[1]; mz += cp[2];
        }
        mx *= (1.0f/KNN); my *= (1.0f/KNN); mz *= (1.0f/KNN);
        double cxx=0, cxy=0, cxz=0, cyy=0, cyz=0, czz=0;
        #pragma unroll
        for (int o = 0; o < KNN; ++o) {
            const float* cp = coord + (size_t)(b*NBP + bi[o]) * 3;
            double dx = (double)cp[0] - (double)mx;
            double dy = (double)cp[1] - (double)my;
            double dz = (double)cp[2] - (double)mz;
            cxx += dx*dx; cxy += dx*dy; cxz += dx*dz;
            cyy += dy*dy; cyz += dy*dz; czz += dz*dz;
        }
        const double inv = 1.0 / (KNN - 1);
        cxx *= inv; cxy *= inv; cxz *= inv; cyy *= inv; cyz *= inv; czz *= inv;

        // analytic eigenvalues of symmetric 3x3 (descending)
        double qm = (cxx + cyy + czz) / 3.0;
        double p1 = cxy*cxy + cxz*cxz + cyz*cyz;
        double b00 = cxx - qm, b11 = cyy - qm, b22 = czz - qm;
        double p2 = b00*b00 + b11*b11 + b22*b22 + 2.0*p1;
        double pp = sqrt(p2 / 6.0);
        double e0, e1, e2;
        if (pp < 1e-30) { e0 = e1 = e2 = qm; }
        else {
            double ip = 1.0 / pp;
            double c00 = b00*ip, c11 = b11*ip, c22 = b22*ip;
            double c01 = cxy*ip, c02 = cxz*ip, c12 = cyz*ip;
            double detB = c00*(c11*c22 - c12*c12)
                        - c01*(c01*c22 - c12*c02)
                        + c02*(c01*c12 - c11*c02);
            double r = detB * 0.5;
            r = fmin(1.0, fmax(-1.0, r));
            double phi = acos(r) / 3.0;
            e0 = qm + 2.0*pp*cos(phi);
            e2 = qm + 2.0*pp*cos(phi + 2.0943951023931953);
            e1 = 3.0*qm - e0 - e2;
        }
        const float lin = (float)((e0 - e1 - e2) / (e0 + e1 + e2 + 1e-6));

        // MLP: 64 -> 32 (BN inference + ReLU) -> 3 -> softmax
        const float* fr = feat + (size_t)gq * 64;
        float h[32];
        #pragma unroll
        for (int j = 0; j < 32; ++j) h[j] = b1[j];
        for (int i = 0; i < 64; ++i) {
            float fi = fr[i];
            #pragma unroll
            for (int j = 0; j < 32; ++j) h[j] = fmaf(fi, W1[i*32 + j], h[j]);
        }
        float l0 = b2[0], l1 = b2[1], l2 = b2[2];
        #pragma unroll
        for (int j = 0; j < 32; ++j) {
            float invstd = 1.0f / sqrtf(rvar[j] + 1e-5f);
            float hb = (h[j] - rmean[j]) * invstd * gmm[j] + bta[j];
            hb = fmaxf(hb, 0.f);
            l0 = fmaf(hb, W2[j*3+0], l0);
            l1 = fmaf(hb, W2[j*3+1], l1);
            l2 = fmaf(hb, W2[j*3+2], l2);
        }
        float m  = fmaxf(l0, fmaxf(l1, l2));
        float x0 = expf(l0 - m), x1 = expf(l1 - m), x2 = expf(l2 - m);
        float es = x0 + x1 + x2;
        float p0 = x0/es, pb = x1/es, pl = x2/es;

        float tower = (density*2.0f + p0) / 3.0f;
        float back  = (fmaxf(1.0f - lin, 1.0f - density) + pb) / 3.0f;
        float line  = (lin*2.0f + pl) / 3.0f;
        // GRID_T=(.1,.1,.1)  GRID_B=(1,1,1)  GRID_L=(.3,.3,1.5)
        float g01 = tower*0.1f + back*1.0f + line*0.3f + 1e-6f;
        float g2  = tower*0.1f + back*1.0f + line*1.5f + 1e-6f;
        out[(size_t)gq*3 + 0] = g01;
        out[(size_t)gq*3 + 1] = g01;
        out[(size_t)gq*3 + 2] = g2;
    }
}

extern "C" void kernel_launch(void* const* d_in, const int* in_sizes, int n_in,
                              void* d_out, int out_size, void* d_ws, size_t ws_size,
                              hipStream_t stream) {
    const float* feat  = (const float*)d_in[0];
    const float* coord = (const float*)d_in[1];
    const float* W1    = (const float*)d_in[3];
    const float* b1    = (const float*)d_in[4];
    const float* gmm   = (const float*)d_in[5];
    const float* bta   = (const float*)d_in[6];
    const float* rmean = (const float*)d_in[7];
    const float* rvar  = (const float*)d_in[8];
    const float* W2    = (const float*)d_in[9];
    const float* b2    = (const float*)d_in[10];
    float* out = (float*)d_out;

    dim3 grid(NBP / QT, NBATCH);   // 625 x 2
    pfas_kernel<<<grid, NTHREADS, 0, stream>>>(feat, coord, W1, b1, gmm, bta,
                                               rmean, rvar, W2, b2, out);
}